// Round 2
// baseline (212.629 us; speedup 1.0000x reference)
//
#include <hip/hip_runtime.h>
#include <math.h>

#define DIMH 256        // D
#define NB   32         // batch
#define E_TOT 43234
#define TE   32         // entities per block (1352 blocks, e-split = traffic-free)
#define DK   16         // dims per chunk
#define NCW  4          // chunks per wave (4 waves x 4 chunks x 16 dims = 256 = D)

typedef float v2f __attribute__((ext_vector_type(2)));
typedef float v4f __attribute__((ext_vector_type(4)));

// Kernel 1: rotate head by relation phase, emit interleaved (re0,re1,im0,im1)
// float4 per (b, dpair). sincos via HW trans unit in REVOLUTIONS:
// phase_rad = rel * (PI/0.03125)  =>  rev = rel * 16 exactly.
__global__ __launch_bounds__(64) void rot_kernel(const float* __restrict__ head,
                                                 const float* __restrict__ rel,
                                                 float4* __restrict__ rot_v4) {
    int i  = blockIdx.x * 64 + threadIdx.x;   // 0..4095
    int b  = i >> 7;
    int dp = i & 127;
    int d0 = dp * 2;
    float4 w;
    {
        float re_h = head[b * 2 * DIMH + d0];
        float im_h = head[b * 2 * DIMH + DIMH + d0];
        float x = rel[b * DIMH + d0] * 16.0f;       // revolutions
        float f = x - floorf(x);
        float s = __builtin_amdgcn_sinf(f);
        float c = __builtin_amdgcn_cosf(f);
        w.x = re_h * c - im_h * s;
        w.z = re_h * s + im_h * c;
    }
    {
        float re_h = head[b * 2 * DIMH + d0 + 1];
        float im_h = head[b * 2 * DIMH + DIMH + d0 + 1];
        float x = rel[b * DIMH + d0 + 1] * 16.0f;
        float f = x - floorf(x);
        float s = __builtin_amdgcn_sinf(f);
        float c = __builtin_amdgcn_cosf(f);
        w.y = re_h * c - im_h * s;
        w.w = re_h * s + im_h * c;
    }
    rot_v4[b * (DIMH / 2) + dp] = w;
}

__device__ __forceinline__ v2f sqrt2(v2f s) {
    v2f r;
    r.x = __builtin_amdgcn_sqrtf(s.x);
    r.y = __builtin_amdgcn_sqrtf(s.y);
    return r;
}

// Kernel 2: 256 thr = 4 waves; TE=32 entities x 32 batches; D SPLIT ACROSS
// WAVES (wave w owns dims [64w,64w+64) as 4 chunks of 16). Each wave stages
// its chunks into a PRIVATE 8 KB LDS zone -> zero barriers in the main loop
// (in-order per-wave DS pipe orders the single-buffer RAW). Per-thread 4x4
// (batch x entity) register tile: 8 ds_read_b128 feed 32 dim-contribs
// = 4 B/dim LDS (round-0 was 8 -> LDS-bound at VALUBusy 53.5% == 26/48).
// Wave count restored vs round-1: 1352 blocks x 4 waves, LDS 32 KB -> 5
// blocks/CU -> ~20 waves/CU (round-1's 1-wave blocks = 5.3 waves/CU killed
// latency hiding: VALUBusy 43%, 97 us).
// XOR swizzle col' = p ^ (row>>2): compute reads hit 8 disjoint 4-bank
// groups (8-lane same-address broadcast each) -> conflict-free; staging
// stores spread evenly over all 32 banks = pure BW floor.
// Epilogue: 2-barrier flat reduction of the 4 per-wave partials via LDS
// (aliases the staging zones, dead by then), coalesced float stores.
__global__ __launch_bounds__(256, 5) void dist_kernel(const float* __restrict__ ent,
                                                      const float4* __restrict__ rot_v4,
                                                      float* __restrict__ out) {
    __shared__ v4f smem[2048];   // 32 KB = 4 waves x (s_e 4 KB + s_r 4 KB)

    const int tid  = threadIdx.x;
    const int lane = tid & 63;
    const int w    = tid >> 6;
    const int eb   = blockIdx.x * TE;
    const int eg   = lane & 7;         // entity group: entities 4eg..4eg+3
    const int bg   = lane >> 3;        // batch group: batches 4bg..4bg+3

    v4f* se = smem + w * 512;          // [32 rows][8 cols] v4f, row = entity
    v4f* sr = se + 256;                // [32 rows][8 cols] v4f, row = batch

    // staging task maps (per wave, per chunk)
    const int erow = lane >> 2;        // ent rows erow, erow+16
    const int eq   = lane & 3;         // float4-quad within the 16-dim chunk
    const int rb   = lane >> 3;        // rot batches rb, rb+8, rb+16, rb+24
    const int rdpi = lane & 7;         // dim-pair within chunk

    const int c0 = w * NCW;            // first global chunk for this wave

    float4 pe_re[2], pe_im[2], pr[4];

    auto load_chunk = [&](int c) {     // c = global chunk id (dims 16c..16c+15)
        const int dk = c * DK;
        #pragma unroll
        for (int s = 0; s < 2; ++s) {
            int er = min(eb + erow + 16 * s, E_TOT - 1);
            const float* b0 = ent + (size_t)er * (2 * DIMH);
            pe_re[s] = *reinterpret_cast<const float4*>(b0 + dk + 4 * eq);
            pe_im[s] = *reinterpret_cast<const float4*>(b0 + DIMH + dk + 4 * eq);
        }
        #pragma unroll
        for (int s = 0; s < 4; ++s)
            pr[s] = rot_v4[(rb + 8 * s) * (DIMH / 2) + c * (DK / 2) + rdpi];
    };

    auto store_chunk = [&]() {
        #pragma unroll
        for (int s = 0; s < 2; ++s) {
            int row = erow + 16 * s;
            int sw  = row >> 2;                      // 0..7
            v4f lo, hi;                              // (re0,re1,im0,im1)
            lo.x = pe_re[s].x; lo.y = pe_re[s].y; lo.z = pe_im[s].x; lo.w = pe_im[s].y;
            hi.x = pe_re[s].z; hi.y = pe_re[s].w; hi.z = pe_im[s].z; hi.w = pe_im[s].w;
            se[row * 8 + ((2 * eq)     ^ sw)] = lo;
            se[row * 8 + ((2 * eq + 1) ^ sw)] = hi;
        }
        #pragma unroll
        for (int s = 0; s < 4; ++s) {
            int b  = rb + 8 * s;
            int sw = b >> 2;                         // 0..7
            v4f r; r.x = pr[s].x; r.y = pr[s].y; r.z = pr[s].z; r.w = pr[s].w;
            sr[b * 8 + (rdpi ^ sw)] = r;
        }
    };

    v2f acc[4][4];   // [batch j][entity k] — static indices only
    #pragma unroll
    for (int j = 0; j < 4; ++j)
        #pragma unroll
        for (int k = 0; k < 4; ++k) { acc[j][k].x = 0.f; acc[j][k].y = 0.f; }

    load_chunk(c0);

    #pragma unroll 1
    for (int cc = 0; cc < NCW; ++cc) {
        store_chunk();                            // regs (chunk c0+cc) -> LDS
        if (cc + 1 < NCW) load_chunk(c0 + cc + 1);

        #pragma unroll 4
        for (int p = 0; p < DK / 2; ++p) {
            int pe = p ^ eg, pb = p ^ bg;
            v4f r0 = sr[(4 * bg + 0) * 8 + pb];
            v4f r1 = sr[(4 * bg + 1) * 8 + pb];
            v4f r2 = sr[(4 * bg + 2) * 8 + pb];
            v4f r3 = sr[(4 * bg + 3) * 8 + pb];
            v4f e0 = se[(4 * eg + 0) * 8 + pe];
            v4f e1 = se[(4 * eg + 1) * 8 + pe];
            v4f e2 = se[(4 * eg + 2) * 8 + pe];
            v4f e3 = se[(4 * eg + 3) * 8 + pe];
            #define CONTRIB(J, K, R, E)                         \
                { v2f a = R.xy - E.xy; v2f b = R.zw - E.zw;     \
                  acc[J][K] += sqrt2(a * a + b * b); }
            CONTRIB(0,0,r0,e0) CONTRIB(0,1,r0,e1) CONTRIB(0,2,r0,e2) CONTRIB(0,3,r0,e3)
            CONTRIB(1,0,r1,e0) CONTRIB(1,1,r1,e1) CONTRIB(1,2,r1,e2) CONTRIB(1,3,r1,e3)
            CONTRIB(2,0,r2,e0) CONTRIB(2,1,r2,e1) CONTRIB(2,2,r2,e2) CONTRIB(2,3,r2,e3)
            CONTRIB(3,0,r3,e0) CONTRIB(3,1,r3,e1) CONTRIB(3,2,r3,e2) CONTRIB(3,3,r3,e3)
            #undef CONTRIB
        }
    }

    // ---- cross-wave reduction: 4 d-partials per (b,e) ----
    float part[16];
    #pragma unroll
    for (int j = 0; j < 4; ++j)
        #pragma unroll
        for (int k = 0; k < 4; ++k)
            part[j * 4 + k] = acc[j][k].x + acc[j][k].y;

    __syncthreads();                       // all waves done reading staging LDS
    float* red = (float*)smem;             // 256 x 17 floats = 17.4 KB < 32 KB
    #pragma unroll
    for (int i = 0; i < 16; ++i)
        red[tid * 17 + i] = part[i];       // stride 17: gcd(17,32)=1 -> ~2-way
    __syncthreads();

    // 1024 outputs, 4/thread; consecutive threads -> consecutive entities
    #pragma unroll
    for (int t = 0; t < 4; ++t) {
        int O  = tid + 256 * t;
        int b  = O >> 5;                   // 0..31
        int ei = O & 31;
        int e  = eb + ei;
        if (e < E_TOT) {
            int lane_src = ((b >> 2) << 3) + (ei >> 2);   // bg*8 + eg
            int idx      = ((b & 3) << 2) + (ei & 3);     // j*4 + k
            float sum = red[(0 * 64 + lane_src) * 17 + idx]
                      + red[(1 * 64 + lane_src) * 17 + idx]
                      + red[(2 * 64 + lane_src) * 17 + idx]
                      + red[(3 * 64 + lane_src) * 17 + idx];
            out[(size_t)b * E_TOT + e] = 6.0f - sum;
        }
    }
}

extern "C" void kernel_launch(void* const* d_in, const int* in_sizes, int n_in,
                              void* d_out, int out_size, void* d_ws, size_t ws_size,
                              hipStream_t stream) {
    const float* head = (const float*)d_in[0];   // (32, 512)
    const float* rel  = (const float*)d_in[1];   // (32, 256)
    const float* ent  = (const float*)d_in[2];   // (43234, 512)
    float4* rot_v4 = (float4*)d_ws;              // 32 * 128 * 16 B = 64 KB

    rot_kernel<<<(NB * DIMH / 2) / 64, 64, 0, stream>>>(head, rel, rot_v4);

    int etiles = (E_TOT + TE - 1) / TE;          // 1352
    dist_kernel<<<etiles, 256, 0, stream>>>(ent, rot_v4, (float*)d_out);
}

// Round 3
// 194.299 us; speedup vs baseline: 1.0943x; 1.0943x over previous
//
#include <hip/hip_runtime.h>
#include <math.h>

#define DIMH 256        // D
#define NB   32         // batch
#define E_TOT 43234
#define TE   32         // entities per block (1352 blocks, e-split = traffic-free)
#define DK   16         // dims per chunk
#define NCW  4          // chunks per wave (4 waves x 4 chunks x 16 dims = 256 = D)

typedef float v2f __attribute__((ext_vector_type(2)));
typedef float v4f __attribute__((ext_vector_type(4)));

// Kernel 1: rotate head by relation phase, emit interleaved (re0,re1,im0,im1)
// float4 per (b, dpair). sincos via HW trans unit in REVOLUTIONS:
// phase_rad = rel * (PI/0.03125)  =>  rev = rel * 16 exactly.
__global__ __launch_bounds__(64) void rot_kernel(const float* __restrict__ head,
                                                 const float* __restrict__ rel,
                                                 float4* __restrict__ rot_v4) {
    int i  = blockIdx.x * 64 + threadIdx.x;   // 0..4095
    int b  = i >> 7;
    int dp = i & 127;
    int d0 = dp * 2;
    float4 w;
    {
        float re_h = head[b * 2 * DIMH + d0];
        float im_h = head[b * 2 * DIMH + DIMH + d0];
        float x = rel[b * DIMH + d0] * 16.0f;       // revolutions
        float f = x - floorf(x);
        float s = __builtin_amdgcn_sinf(f);
        float c = __builtin_amdgcn_cosf(f);
        w.x = re_h * c - im_h * s;
        w.z = re_h * s + im_h * c;
    }
    {
        float re_h = head[b * 2 * DIMH + d0 + 1];
        float im_h = head[b * 2 * DIMH + DIMH + d0 + 1];
        float x = rel[b * DIMH + d0 + 1] * 16.0f;
        float f = x - floorf(x);
        float s = __builtin_amdgcn_sinf(f);
        float c = __builtin_amdgcn_cosf(f);
        w.y = re_h * c - im_h * s;
        w.w = re_h * s + im_h * c;
    }
    rot_v4[b * (DIMH / 2) + dp] = w;
}

__device__ __forceinline__ v2f sqrt2(v2f s) {
    v2f r;
    r.x = __builtin_amdgcn_sqrtf(s.x);
    r.y = __builtin_amdgcn_sqrtf(s.y);
    return r;
}

// Kernel 2: 256 thr = 4 waves; TE=32 entities x 32 batches; D split across
// waves (wave w owns dims [64w,64w+64) as 4 chunks of 16), each staged into
// a PRIVATE 8 KB LDS zone -> zero barriers in the main loop. Per-thread 4x4
// (batch x entity) register tile: 8 ds_read_b128 feed 32 dim-contribs
// = 4 B/dim LDS.
// launch_bounds (256, 4): ROUND-2 POST-MORTEM — (256,5) forced VGPR 48 vs
// the ~96 natural demand -> 190 MB of scratch spill traffic (WRITE_SIZE
// 128 MB vs 5.5 MB output), kernel went HBM-bound at 2.5 TB/s. Cap 128
// removes the spill; compiler's natural ~96-102 VGPR still permits 5
// waves/EU, LDS 32 KB permits 5 blocks/CU = grid's 5.28 -> ~20 waves/CU.
// XOR swizzle col' = p ^ (row>>2): compute reads hit 8 disjoint 4-bank
// groups (8-lane broadcast each) -> conflict-free; staging stores spread
// evenly over 32 banks.
// Epilogue: 2-barrier flat LDS reduction of the 4 per-wave d-partials
// (aliases dead staging zones), coalesced stores.
__global__ __launch_bounds__(256, 4) void dist_kernel(const float* __restrict__ ent,
                                                      const float4* __restrict__ rot_v4,
                                                      float* __restrict__ out) {
    __shared__ v4f smem[2048];   // 32 KB = 4 waves x (s_e 4 KB + s_r 4 KB)

    const int tid  = threadIdx.x;
    const int lane = tid & 63;
    const int w    = tid >> 6;
    const int eb   = blockIdx.x * TE;
    const int eg   = lane & 7;         // entity group: entities 4eg..4eg+3
    const int bg   = lane >> 3;        // batch group: batches 4bg..4bg+3

    v4f* se = smem + w * 512;          // [32 rows][8 cols] v4f, row = entity
    v4f* sr = se + 256;                // [32 rows][8 cols] v4f, row = batch

    // staging task maps (per wave, per chunk)
    const int erow = lane >> 2;        // ent rows erow, erow+16
    const int eq   = lane & 3;         // float4-quad within the 16-dim chunk
    const int rb   = lane >> 3;        // rot batches rb, rb+8, rb+16, rb+24
    const int rdpi = lane & 7;         // dim-pair within chunk

    const int c0 = w * NCW;            // first global chunk for this wave

    float4 pe_re[2], pe_im[2], pr[4];

    auto load_chunk = [&](int c) {     // c = global chunk id (dims 16c..16c+15)
        const int dk = c * DK;
        #pragma unroll
        for (int s = 0; s < 2; ++s) {
            int er = min(eb + erow + 16 * s, E_TOT - 1);
            const float* b0 = ent + (size_t)er * (2 * DIMH);
            pe_re[s] = *reinterpret_cast<const float4*>(b0 + dk + 4 * eq);
            pe_im[s] = *reinterpret_cast<const float4*>(b0 + DIMH + dk + 4 * eq);
        }
        #pragma unroll
        for (int s = 0; s < 4; ++s)
            pr[s] = rot_v4[(rb + 8 * s) * (DIMH / 2) + c * (DK / 2) + rdpi];
    };

    auto store_chunk = [&]() {
        #pragma unroll
        for (int s = 0; s < 2; ++s) {
            int row = erow + 16 * s;
            int sw  = row >> 2;                      // 0..7
            v4f lo, hi;                              // (re0,re1,im0,im1)
            lo.x = pe_re[s].x; lo.y = pe_re[s].y; lo.z = pe_im[s].x; lo.w = pe_im[s].y;
            hi.x = pe_re[s].z; hi.y = pe_re[s].w; hi.z = pe_im[s].z; hi.w = pe_im[s].w;
            se[row * 8 + ((2 * eq)     ^ sw)] = lo;
            se[row * 8 + ((2 * eq + 1) ^ sw)] = hi;
        }
        #pragma unroll
        for (int s = 0; s < 4; ++s) {
            int b  = rb + 8 * s;
            int sw = b >> 2;                         // 0..7
            v4f r; r.x = pr[s].x; r.y = pr[s].y; r.z = pr[s].z; r.w = pr[s].w;
            sr[b * 8 + (rdpi ^ sw)] = r;
        }
    };

    v2f acc[4][4];   // [batch j][entity k] — static indices only
    #pragma unroll
    for (int j = 0; j < 4; ++j)
        #pragma unroll
        for (int k = 0; k < 4; ++k) { acc[j][k].x = 0.f; acc[j][k].y = 0.f; }

    load_chunk(c0);

    #pragma unroll 1
    for (int cc = 0; cc < NCW; ++cc) {
        store_chunk();                            // regs (chunk c0+cc) -> LDS
        if (cc + 1 < NCW) load_chunk(c0 + cc + 1);

        #pragma unroll 4
        for (int p = 0; p < DK / 2; ++p) {
            int pe = p ^ eg, pb = p ^ bg;
            v4f r0 = sr[(4 * bg + 0) * 8 + pb];
            v4f r1 = sr[(4 * bg + 1) * 8 + pb];
            v4f r2 = sr[(4 * bg + 2) * 8 + pb];
            v4f r3 = sr[(4 * bg + 3) * 8 + pb];
            v4f e0 = se[(4 * eg + 0) * 8 + pe];
            v4f e1 = se[(4 * eg + 1) * 8 + pe];
            v4f e2 = se[(4 * eg + 2) * 8 + pe];
            v4f e3 = se[(4 * eg + 3) * 8 + pe];
            #define CONTRIB(J, K, R, E)                         \
                { v2f a = R.xy - E.xy; v2f b = R.zw - E.zw;     \
                  acc[J][K] += sqrt2(a * a + b * b); }
            CONTRIB(0,0,r0,e0) CONTRIB(0,1,r0,e1) CONTRIB(0,2,r0,e2) CONTRIB(0,3,r0,e3)
            CONTRIB(1,0,r1,e0) CONTRIB(1,1,r1,e1) CONTRIB(1,2,r1,e2) CONTRIB(1,3,r1,e3)
            CONTRIB(2,0,r2,e0) CONTRIB(2,1,r2,e1) CONTRIB(2,2,r2,e2) CONTRIB(2,3,r2,e3)
            CONTRIB(3,0,r3,e0) CONTRIB(3,1,r3,e1) CONTRIB(3,2,r3,e2) CONTRIB(3,3,r3,e3)
            #undef CONTRIB
        }
    }

    // ---- cross-wave reduction: 4 d-partials per (b,e) ----
    float part[16];
    #pragma unroll
    for (int j = 0; j < 4; ++j)
        #pragma unroll
        for (int k = 0; k < 4; ++k)
            part[j * 4 + k] = acc[j][k].x + acc[j][k].y;

    __syncthreads();                       // all waves done reading staging LDS
    float* red = (float*)smem;             // 256 x 17 floats = 17.4 KB < 32 KB
    #pragma unroll
    for (int i = 0; i < 16; ++i)
        red[tid * 17 + i] = part[i];       // stride 17: gcd(17,32)=1 -> ~2-way
    __syncthreads();

    // 1024 outputs, 4/thread; consecutive threads -> consecutive entities
    #pragma unroll
    for (int t = 0; t < 4; ++t) {
        int O  = tid + 256 * t;
        int b  = O >> 5;                   // 0..31
        int ei = O & 31;
        int e  = eb + ei;
        if (e < E_TOT) {
            int lane_src = ((b >> 2) << 3) + (ei >> 2);   // bg*8 + eg
            int idx      = ((b & 3) << 2) + (ei & 3);     // j*4 + k
            float sum = red[(0 * 64 + lane_src) * 17 + idx]
                      + red[(1 * 64 + lane_src) * 17 + idx]
                      + red[(2 * 64 + lane_src) * 17 + idx]
                      + red[(3 * 64 + lane_src) * 17 + idx];
            out[(size_t)b * E_TOT + e] = 6.0f - sum;
        }
    }
}

extern "C" void kernel_launch(void* const* d_in, const int* in_sizes, int n_in,
                              void* d_out, int out_size, void* d_ws, size_t ws_size,
                              hipStream_t stream) {
    const float* head = (const float*)d_in[0];   // (32, 512)
    const float* rel  = (const float*)d_in[1];   // (32, 256)
    const float* ent  = (const float*)d_in[2];   // (43234, 512)
    float4* rot_v4 = (float4*)d_ws;              // 32 * 128 * 16 B = 64 KB

    rot_kernel<<<(NB * DIMH / 2) / 64, 64, 0, stream>>>(head, rel, rot_v4);

    int etiles = (E_TOT + TE - 1) / TE;          // 1352
    dist_kernel<<<etiles, 256, 0, stream>>>(ent, rot_v4, (float*)d_out);
}

// Round 5
// 171.007 us; speedup vs baseline: 1.2434x; 1.1362x over previous
//
#include <hip/hip_runtime.h>
#include <math.h>

#define DIMH 256        // D
#define NB   32         // batch
#define E_TOT 43234
#define TE   32         // entities per block (1352 blocks, e-split = traffic-free)
#define DK   16         // dims per chunk
#define NCW  4          // chunks per wave (4 waves x 4 chunks x 16 dims = 256 = D)

typedef float v2f __attribute__((ext_vector_type(2)));
typedef float v4f __attribute__((ext_vector_type(4)));

// Kernel 1: rotate head by relation phase, emit interleaved (re0,re1,im0,im1)
// float4 per (b, dpair). sincos via HW trans unit in REVOLUTIONS:
// phase_rad = rel * (PI/0.03125)  =>  rev = rel * 16 exactly.
__global__ __launch_bounds__(64) void rot_kernel(const float* __restrict__ head,
                                                 const float* __restrict__ rel,
                                                 float4* __restrict__ rot_v4) {
    int i  = blockIdx.x * 64 + threadIdx.x;   // 0..4095
    int b  = i >> 7;
    int dp = i & 127;
    int d0 = dp * 2;
    float4 w;
    {
        float re_h = head[b * 2 * DIMH + d0];
        float im_h = head[b * 2 * DIMH + DIMH + d0];
        float x = rel[b * DIMH + d0] * 16.0f;       // revolutions
        float f = x - floorf(x);
        float s = __builtin_amdgcn_sinf(f);
        float c = __builtin_amdgcn_cosf(f);
        w.x = re_h * c - im_h * s;
        w.z = re_h * s + im_h * c;
    }
    {
        float re_h = head[b * 2 * DIMH + d0 + 1];
        float im_h = head[b * 2 * DIMH + DIMH + d0 + 1];
        float x = rel[b * DIMH + d0 + 1] * 16.0f;
        float f = x - floorf(x);
        float s = __builtin_amdgcn_sinf(f);
        float c = __builtin_amdgcn_cosf(f);
        w.y = re_h * c - im_h * s;
        w.w = re_h * s + im_h * c;
    }
    rot_v4[b * (DIMH / 2) + dp] = w;
}

__device__ __forceinline__ v2f sqrt2(v2f s) {
    v2f r;
    r.x = __builtin_amdgcn_sqrtf(s.x);
    r.y = __builtin_amdgcn_sqrtf(s.y);
    return r;
}

// Kernel 2: 256 thr = 4 waves; TE=32 entities x 32 batches; D split across
// waves (wave w owns dims [64w,64w+64) as 4 chunks of 16), each staged into
// a PRIVATE 8 KB LDS zone -> zero barriers in the main loop. Per-thread 4x4
// (batch x entity) register tile: 8 ds_read_b128 feed 32 dim-contribs
// = 4 B/dim LDS.
// launch_bounds (256, 2): ROUNDS 2-3 POST-MORTEM — empirically this
// backend's per-wave arch-VGPR budget is 256/min_waves (NOT 512/min):
// (256,5) gave 48 VGPR, (256,4) gave 64 VGPR, both spilling 50-190 MB of
// scratch traffic (WRITE_SIZE 55-128 MB vs 5.5 MB output). min=2 -> budget
// 128 >= ~96-110 natural demand -> ZERO spill. Runtime occupancy is set by
// actual resources, not the bound: ~96-104 VGPR -> 5 waves/EU, LDS 32 KB
// -> 5 blocks/CU = 20 waves/CU, matching the 5.28 blocks/CU grid.
// XOR swizzle col' = p ^ (row>>2): compute reads hit 8 disjoint 4-bank
// groups (8-lane broadcast each) -> conflict-free; staging stores spread
// evenly over 32 banks.
// Epilogue: 2-barrier flat LDS reduction of the 4 per-wave d-partials
// (aliases dead staging zones), coalesced stores.
__global__ __launch_bounds__(256, 2) void dist_kernel(const float* __restrict__ ent,
                                                      const float4* __restrict__ rot_v4,
                                                      float* __restrict__ out) {
    __shared__ v4f smem[2048];   // 32 KB = 4 waves x (s_e 4 KB + s_r 4 KB)

    const int tid  = threadIdx.x;
    const int lane = tid & 63;
    const int w    = tid >> 6;
    const int eb   = blockIdx.x * TE;
    const int eg   = lane & 7;         // entity group: entities 4eg..4eg+3
    const int bg   = lane >> 3;        // batch group: batches 4bg..4bg+3

    v4f* se = smem + w * 512;          // [32 rows][8 cols] v4f, row = entity
    v4f* sr = se + 256;                // [32 rows][8 cols] v4f, row = batch

    // staging task maps (per wave, per chunk)
    const int erow = lane >> 2;        // ent rows erow, erow+16
    const int eq   = lane & 3;         // float4-quad within the 16-dim chunk
    const int rb   = lane >> 3;        // rot batches rb, rb+8, rb+16, rb+24
    const int rdpi = lane & 7;         // dim-pair within chunk

    const int c0 = w * NCW;            // first global chunk for this wave

    float4 pe_re[2], pe_im[2], pr[4];

    auto load_chunk = [&](int c) {     // c = global chunk id (dims 16c..16c+15)
        const int dk = c * DK;
        #pragma unroll
        for (int s = 0; s < 2; ++s) {
            int er = min(eb + erow + 16 * s, E_TOT - 1);
            const float* b0 = ent + (size_t)er * (2 * DIMH);
            pe_re[s] = *reinterpret_cast<const float4*>(b0 + dk + 4 * eq);
            pe_im[s] = *reinterpret_cast<const float4*>(b0 + DIMH + dk + 4 * eq);
        }
        #pragma unroll
        for (int s = 0; s < 4; ++s)
            pr[s] = rot_v4[(rb + 8 * s) * (DIMH / 2) + c * (DK / 2) + rdpi];
    };

    auto store_chunk = [&]() {
        #pragma unroll
        for (int s = 0; s < 2; ++s) {
            int row = erow + 16 * s;
            int sw  = row >> 2;                      // 0..7
            v4f lo, hi;                              // (re0,re1,im0,im1)
            lo.x = pe_re[s].x; lo.y = pe_re[s].y; lo.z = pe_im[s].x; lo.w = pe_im[s].y;
            hi.x = pe_re[s].z; hi.y = pe_re[s].w; hi.z = pe_im[s].z; hi.w = pe_im[s].w;
            se[row * 8 + ((2 * eq)     ^ sw)] = lo;
            se[row * 8 + ((2 * eq + 1) ^ sw)] = hi;
        }
        #pragma unroll
        for (int s = 0; s < 4; ++s) {
            int b  = rb + 8 * s;
            int sw = b >> 2;                         // 0..7
            v4f r; r.x = pr[s].x; r.y = pr[s].y; r.z = pr[s].z; r.w = pr[s].w;
            sr[b * 8 + (rdpi ^ sw)] = r;
        }
    };

    v2f acc[4][4];   // [batch j][entity k] — static indices only
    #pragma unroll
    for (int j = 0; j < 4; ++j)
        #pragma unroll
        for (int k = 0; k < 4; ++k) { acc[j][k].x = 0.f; acc[j][k].y = 0.f; }

    load_chunk(c0);

    #pragma unroll 1
    for (int cc = 0; cc < NCW; ++cc) {
        store_chunk();                            // regs (chunk c0+cc) -> LDS
        if (cc + 1 < NCW) load_chunk(c0 + cc + 1);

        #pragma unroll 4
        for (int p = 0; p < DK / 2; ++p) {
            int pe = p ^ eg, pb = p ^ bg;
            v4f r0 = sr[(4 * bg + 0) * 8 + pb];
            v4f r1 = sr[(4 * bg + 1) * 8 + pb];
            v4f r2 = sr[(4 * bg + 2) * 8 + pb];
            v4f r3 = sr[(4 * bg + 3) * 8 + pb];
            v4f e0 = se[(4 * eg + 0) * 8 + pe];
            v4f e1 = se[(4 * eg + 1) * 8 + pe];
            v4f e2 = se[(4 * eg + 2) * 8 + pe];
            v4f e3 = se[(4 * eg + 3) * 8 + pe];
            #define CONTRIB(J, K, R, E)                         \
                { v2f a = R.xy - E.xy; v2f b = R.zw - E.zw;     \
                  acc[J][K] += sqrt2(a * a + b * b); }
            CONTRIB(0,0,r0,e0) CONTRIB(0,1,r0,e1) CONTRIB(0,2,r0,e2) CONTRIB(0,3,r0,e3)
            CONTRIB(1,0,r1,e0) CONTRIB(1,1,r1,e1) CONTRIB(1,2,r1,e2) CONTRIB(1,3,r1,e3)
            CONTRIB(2,0,r2,e0) CONTRIB(2,1,r2,e1) CONTRIB(2,2,r2,e2) CONTRIB(2,3,r2,e3)
            CONTRIB(3,0,r3,e0) CONTRIB(3,1,r3,e1) CONTRIB(3,2,r3,e2) CONTRIB(3,3,r3,e3)
            #undef CONTRIB
        }
    }

    // ---- cross-wave reduction: 4 d-partials per (b,e) ----
    float part[16];
    #pragma unroll
    for (int j = 0; j < 4; ++j)
        #pragma unroll
        for (int k = 0; k < 4; ++k)
            part[j * 4 + k] = acc[j][k].x + acc[j][k].y;

    __syncthreads();                       // all waves done reading staging LDS
    float* red = (float*)smem;             // 256 x 17 floats = 17.4 KB < 32 KB
    #pragma unroll
    for (int i = 0; i < 16; ++i)
        red[tid * 17 + i] = part[i];       // stride 17: gcd(17,32)=1 -> ~2-way
    __syncthreads();

    // 1024 outputs, 4/thread; consecutive threads -> consecutive entities
    #pragma unroll
    for (int t = 0; t < 4; ++t) {
        int O  = tid + 256 * t;
        int b  = O >> 5;                   // 0..31
        int ei = O & 31;
        int e  = eb + ei;
        if (e < E_TOT) {
            int lane_src = ((b >> 2) << 3) + (ei >> 2);   // bg*8 + eg
            int idx      = ((b & 3) << 2) + (ei & 3);     // j*4 + k
            float sum = red[(0 * 64 + lane_src) * 17 + idx]
                      + red[(1 * 64 + lane_src) * 17 + idx]
                      + red[(2 * 64 + lane_src) * 17 + idx]
                      + red[(3 * 64 + lane_src) * 17 + idx];
            out[(size_t)b * E_TOT + e] = 6.0f - sum;
        }
    }
}

extern "C" void kernel_launch(void* const* d_in, const int* in_sizes, int n_in,
                              void* d_out, int out_size, void* d_ws, size_t ws_size,
                              hipStream_t stream) {
    const float* head = (const float*)d_in[0];   // (32, 512)
    const float* rel  = (const float*)d_in[1];   // (32, 256)
    const float* ent  = (const float*)d_in[2];   // (43234, 512)
    float4* rot_v4 = (float4*)d_ws;              // 32 * 128 * 16 B = 64 KB

    rot_kernel<<<(NB * DIMH / 2) / 64, 64, 0, stream>>>(head, rel, rot_v4);

    int etiles = (E_TOT + TE - 1) / TE;          // 1352
    dist_kernel<<<etiles, 256, 0, stream>>>(ent, rot_v4, (float*)d_out);
}